// Round 3
// baseline (1828.044 us; speedup 1.0000x reference)
//
#include <hip/hip_runtime.h>
#include <hip/hip_bf16.h>
#include <math.h>

#define N_NODES 200000
#define N_EDGES 5000000
#define NFEAT 16
#define DIM 10
#define DIMP 11          // LDS agg row stride (breaks bank pattern: gcd(11,32)=1)
#define HPAD 16          // padded h-row stride in floats -> 64B rows, 1 line per gather
#define NGRAPH 1000
#define BSH 8            // 256 nodes per bucket
#define BNODES 256
#define NB ((N_NODES + BNODES - 1) / BNODES)   // 782
#define CBLK 320         // scatter blocks (5M/320 = 15625 edges each, exact)

// ---------- pass A: per-bucket edge histogram ----------
__global__ void bucket_count(const int* __restrict__ dst, int* __restrict__ bcount) {
    __shared__ int h[NB];
    for (int t = threadIdx.x; t < NB; t += blockDim.x) h[t] = 0;
    __syncthreads();
    int stride = gridDim.x * blockDim.x;
    for (int e = blockIdx.x * blockDim.x + threadIdx.x; e < N_EDGES; e += stride)
        atomicAdd(&h[dst[e] >> BSH], 1);
    __syncthreads();
    for (int t = threadIdx.x; t < NB; t += blockDim.x)
        if (h[t]) atomicAdd(&bcount[t], h[t]);
}

// ---------- pass B: exclusive scan over 782 buckets ----------
__global__ void bucket_scan(const int* __restrict__ bcount,
                            int* __restrict__ bstart, int* __restrict__ bcursor) {
    __shared__ int s[NB];
    int t = threadIdx.x;
    if (t < NB) s[t] = bcount[t];
    __syncthreads();
    if (t == 0) {
        int acc = 0;
        for (int i = 0; i < NB; i++) { int c = s[i]; s[i] = acc; acc += c; }
    }
    __syncthreads();
    if (t < NB) { bstart[t] = s[t]; bcursor[t] = s[t]; }
    if (t == 0) bstart[NB] = N_EDGES;
}

// ---------- pass C: scatter edges into bucket segments, packed (src<<8)|dstLocal ----------
__global__ void bucket_scatter(const int* __restrict__ src, const int* __restrict__ dst,
                               int* __restrict__ bcursor, unsigned int* __restrict__ packed) {
    __shared__ int h[NB];
    __shared__ int wp[NB];
    for (int t = threadIdx.x; t < NB; t += blockDim.x) h[t] = 0;
    __syncthreads();
    int per = (N_EDGES + gridDim.x - 1) / gridDim.x;
    int e0 = blockIdx.x * per;
    int e1 = e0 + per; if (e1 > N_EDGES) e1 = N_EDGES;
    for (int e = e0 + threadIdx.x; e < e1; e += blockDim.x)
        atomicAdd(&h[dst[e] >> BSH], 1);
    __syncthreads();
    for (int t = threadIdx.x; t < NB; t += blockDim.x) {
        int c = h[t];
        wp[t] = c ? atomicAdd(&bcursor[t], c) : 0;   // reserve global range
    }
    __syncthreads();
    for (int e = e0 + threadIdx.x; e < e1; e += blockDim.x) {
        int d = dst[e];
        int b = d >> BSH;
        int r = atomicAdd(&wp[b], 1);                // LDS bump -> global slot
        packed[r] = ((unsigned)src[e] << BSH) | (unsigned)(d & (BNODES - 1));
    }
}

// ---------- y = x @ w1_1 (pre-apply layer-1 first matmul), padded rows ----------
__global__ void xform_kernel(const float* __restrict__ x,
                             const float* __restrict__ w1,   // [16][10]
                             float* __restrict__ y) {        // [N][HPAD]
    int i = blockIdx.x * blockDim.x + threadIdx.x;
    if (i >= N_NODES) return;
    float xi[NFEAT];
    const float4* xr = reinterpret_cast<const float4*>(x + (size_t)i * NFEAT);
#pragma unroll
    for (int q = 0; q < 4; q++) {
        float4 v = xr[q];
        xi[q*4+0] = v.x; xi[q*4+1] = v.y; xi[q*4+2] = v.z; xi[q*4+3] = v.w;
    }
    float o[DIM];
#pragma unroll
    for (int j = 0; j < DIM; j++) {
        float s = 0.f;
#pragma unroll
        for (int f = 0; f < NFEAT; f++) s += xi[f] * w1[f * DIM + j];
        o[j] = s;
    }
    float* yr = y + (size_t)i * HPAD;
    *(float4*)yr       = make_float4(o[0], o[1], o[2], o[3]);
    *(float4*)(yr + 4) = make_float4(o[4], o[5], o[6], o[7]);
    *(float2*)(yr + 8) = make_float2(o[8], o[9]);
}

// ---------- pass D: per-bucket LDS aggregation + MLP + pool ----------
template <bool FIRST>
__global__ void __launch_bounds__(BNODES)
gin_layer(const float* __restrict__ hin,               // [N][HPAD]
          const unsigned int* __restrict__ packed,
          const int* __restrict__ bstart,
          const float* __restrict__ w1, const float* __restrict__ b1,
          const float* __restrict__ w2, const float* __restrict__ b2,
          const int* __restrict__ batch,
          float* __restrict__ hout,                    // [N][HPAD]
          float* __restrict__ pooled) {                // [G][10] layer slice
    __shared__ float agg[BNODES][DIMP];
    __shared__ float wts[2][DIM * DIM];
    __shared__ float bias[2][DIM];
    __shared__ int gidb[BNODES];
    int tid = threadIdx.x;
    int b = blockIdx.x;
    int n0 = b << BSH;
    int nn = N_NODES - n0; if (nn > BNODES) nn = BNODES;

    for (int t = tid; t < BNODES * DIMP; t += blockDim.x) ((float*)agg)[t] = 0.f;
    if (!FIRST) for (int t = tid; t < DIM * DIM; t += blockDim.x) wts[0][t] = w1[t];
    for (int t = tid; t < DIM * DIM; t += blockDim.x) wts[1][t] = w2[t];
    if (tid < DIM) { bias[0][tid] = b1[tid]; bias[1][tid] = b2[tid]; }
    __syncthreads();

    int e0 = bstart[b], e1 = bstart[b + 1];
    for (int e = e0 + tid; e < e1; e += blockDim.x) {
        unsigned p = packed[e];
        int s = p >> BSH;
        int dl = p & (BNODES - 1);
        const float* row = hin + (size_t)s * HPAD;
        float4 v0 = *(const float4*)row;
        float4 v1 = *(const float4*)(row + 4);
        float2 v2 = *(const float2*)(row + 8);
        atomicAdd(&agg[dl][0], v0.x); atomicAdd(&agg[dl][1], v0.y);
        atomicAdd(&agg[dl][2], v0.z); atomicAdd(&agg[dl][3], v0.w);
        atomicAdd(&agg[dl][4], v1.x); atomicAdd(&agg[dl][5], v1.y);
        atomicAdd(&agg[dl][6], v1.z); atomicAdd(&agg[dl][7], v1.w);
        atomicAdd(&agg[dl][8], v2.x); atomicAdd(&agg[dl][9], v2.y);
    }
    __syncthreads();

    float hv[DIM];
    int i = n0 + tid;
    if (tid < nn) {
        const float* hr = hin + (size_t)i * HPAD;
        float z[DIM];
#pragma unroll
        for (int j = 0; j < DIM; j++) z[j] = hr[j] + agg[tid][j];
        float t1[DIM];
        if (FIRST) {
#pragma unroll
            for (int j = 0; j < DIM; j++) { float v = z[j] + bias[0][j]; t1[j] = v > 0.f ? v : 0.f; }
        } else {
#pragma unroll
            for (int j = 0; j < DIM; j++) {
                float s = bias[0][j];
#pragma unroll
                for (int f = 0; f < DIM; f++) s += z[f] * wts[0][f * DIM + j];
                t1[j] = s > 0.f ? s : 0.f;
            }
        }
#pragma unroll
        for (int j = 0; j < DIM; j++) {
            float s = bias[1][j];
#pragma unroll
            for (int f = 0; f < DIM; f++) s += t1[f] * wts[1][f * DIM + j];
            hv[j] = s > 0.f ? s : 0.f;
        }
        float* ho = hout + (size_t)i * HPAD;
        *(float4*)ho       = make_float4(hv[0], hv[1], hv[2], hv[3]);
        *(float4*)(ho + 4) = make_float4(hv[4], hv[5], hv[6], hv[7]);
        *(float2*)(ho + 8) = make_float2(hv[8], hv[9]);
        gidb[tid] = batch[i];
    }
    __syncthreads();
    if (tid < nn) {
#pragma unroll
        for (int j = 0; j < DIM; j++) agg[tid][j] = hv[j];   // reuse agg as pool stage
    }
    __syncthreads();

    // per-wave run-length pool reduction (batch sorted -> few runs)
    int wv = tid >> 6, lane = tid & 63;
    int s0 = wv * 64;
    if (lane < DIM && s0 < nn) {
        int send = s0 + 64; if (send > nn) send = nn;
        int cg = gidb[s0];
        float acc = agg[s0][lane];
        for (int n = s0 + 1; n < send; n++) {
            int g = gidb[n];
            float v = agg[n][lane];
            if (g == cg) acc += v;
            else { atomicAdd(&pooled[cg * DIM + lane], acc); cg = g; acc = v; }
        }
        atomicAdd(&pooled[cg * DIM + lane], acc);
    }
}

// ---------- readout: counts via binary search on sorted batch ----------
__global__ void final_kernel(const float* __restrict__ pooled,  // [5][G][10]
                             const int* __restrict__ batch,
                             const float* __restrict__ lw,      // [5][10]
                             float* __restrict__ out) {
    int g = blockIdx.x * blockDim.x + threadIdx.x;
    if (g >= NGRAPH) return;
    int lo = 0, hi = N_NODES;
    while (lo < hi) { int m = (lo + hi) >> 1; if (batch[m] < g) lo = m + 1; else hi = m; }
    int a = lo;
    hi = N_NODES;
    while (lo < hi) { int m = (lo + hi) >> 1; if (batch[m] < g + 1) lo = m + 1; else hi = m; }
    float c = (float)(lo - a);
    float inv = 1.0f / (c > 1.f ? c : 1.f);
    float s = 0.f;
#pragma unroll
    for (int l = 0; l < 5; l++) {
        float d = 0.f;
#pragma unroll
        for (int j = 0; j < DIM; j++)
            d += pooled[(size_t)l * NGRAPH * DIM + (size_t)g * DIM + j] * lw[l * DIM + j];
        s += d * inv;
    }
    out[g] = 1.0f / (1.0f + expf(-s));
}

extern "C" void kernel_launch(void* const* d_in, const int* in_sizes, int n_in,
                              void* d_out, int out_size, void* d_ws, size_t ws_size,
                              hipStream_t stream) {
    const float* x    = (const float*)d_in[0];
    const int*   ei   = (const int*)d_in[1];
    const int*   batch= (const int*)d_in[2];
    const float* w1_1 = (const float*)d_in[3];
    const float* b1_1 = (const float*)d_in[4];
    const float* w2_1 = (const float*)d_in[5];
    const float* b2_1 = (const float*)d_in[6];
    const float* ws1  = (const float*)d_in[7];   // [4][10][10]
    const float* bs1  = (const float*)d_in[8];   // [4][10]
    const float* ws2  = (const float*)d_in[9];   // [4][10][10]
    const float* bs2  = (const float*)d_in[10];  // [4][10]
    const float* lw   = (const float*)d_in[11];  // [5][10]
    float* out = (float*)d_out;

    const int* src = ei;
    const int* dst = ei + N_EDGES;

    // ---- workspace layout ----
    int* bcount   = (int*)d_ws;                         // [NB]
    int* bstart   = bcount + NB;                        // [NB+1]
    int* bcursor  = bstart + NB + 1;                    // [NB]
    unsigned int* packed = (unsigned int*)(bcursor + NB + 13); // align-ish, [E]
    float* ybuf   = (float*)(packed + N_EDGES);         // [N][HPAD]
    float* hbuf   = ybuf + (size_t)N_NODES * HPAD;      // [N][HPAD]
    float* pooled = hbuf + (size_t)N_NODES * HPAD;      // [5][G][10]
    size_t needed = (size_t)((char*)(pooled + 5 * NGRAPH * DIM) - (char*)d_ws);
    if (needed > ws_size) return;  // loud failure (output stays zero)

    const int TB = 256;
    int nblocks = (N_NODES + TB - 1) / TB;
    int gblocks = (NGRAPH + TB - 1) / TB;

    hipMemsetAsync(bcount, 0, NB * sizeof(int), stream);
    hipMemsetAsync(pooled, 0, (size_t)5 * NGRAPH * DIM * sizeof(float), stream);

    // ---- semi-sort edges by 256-node bucket ----
    bucket_count<<<384, TB, 0, stream>>>(dst, bcount);
    bucket_scan<<<1, 1024, 0, stream>>>(bcount, bstart, bcursor);
    bucket_scatter<<<CBLK, TB, 0, stream>>>(src, dst, bcursor, packed);

    // ---- layer 1 (pre-applied w1) ----
    xform_kernel<<<nblocks, TB, 0, stream>>>(x, w1_1, ybuf);
    gin_layer<true><<<NB, BNODES, 0, stream>>>(ybuf, packed, bstart,
        nullptr, b1_1, w2_1, b2_1, batch, hbuf, pooled);

    // ---- layers 2..5 (ping-pong) ----
    float* hin = hbuf;
    float* hout = ybuf;
    for (int l = 0; l < 4; l++) {
        gin_layer<false><<<NB, BNODES, 0, stream>>>(hin, packed, bstart,
            ws1 + (size_t)l * DIM * DIM, bs1 + (size_t)l * DIM,
            ws2 + (size_t)l * DIM * DIM, bs2 + (size_t)l * DIM,
            batch, hout, pooled + (size_t)(l + 1) * NGRAPH * DIM);
        float* tmp = hin; hin = hout; hout = tmp;
    }

    // ---- readout ----
    final_kernel<<<gblocks, TB, 0, stream>>>(pooled, batch, lw, out);
}